// Round 1
// baseline (118.887 us; speedup 1.0000x reference)
//
#include <hip/hip_runtime.h>

#define LSEQ 8192
#define NF 9
#define NT 1024
#define ITEMS 8   // LSEQ / NT
#define NW 16     // waves per block

__device__ __forceinline__ float f4c(const float4& v, int c) {
    return c == 0 ? v.x : c == 1 ? v.y : c == 2 ? v.z : v.w;
}

// Block-wide exclusive scan of per-thread totals (double). s16 = 16-double scratch.
// Returns this thread's exclusive prefix; *blockTot = total over the block.
__device__ __forceinline__ double block_scan(double tot, int lane, int wid,
                                             double* s16, double* blockTot) {
    double v = tot;
    #pragma unroll
    for (int off = 1; off < 64; off <<= 1) {
        double n = __shfl_up(v, (unsigned)off, 64);
        if (lane >= off) v += n;
    }
    if (lane == 63) s16[wid] = v;   // wave-inclusive total
    __syncthreads();
    double wOff = 0.0, bTot = 0.0;
    #pragma unroll
    for (int w = 0; w < NW; ++w) {
        double t2 = s16[w];
        if (w < wid) wOff += t2;
        bTot += t2;
    }
    __syncthreads();                // scratch region reusable after this
    *blockTot = bTot;
    return wOff + (v - tot);
}

__global__ __launch_bounds__(NT) void kenneth_kernel(const float* __restrict__ conc,
                                                     const float* __restrict__ kern,
                                                     float* __restrict__ out) {
    __shared__ __align__(16) float Zp[LSEQ];   // znow prefix (+1), f32
    __shared__ __align__(16) float PB[LSEQ];   // holds PP, then prefQ

    const int b = blockIdx.x;
    const int tid = threadIdx.x;
    const int lane = tid & 63;
    const int wid = tid >> 6;
    const int t0 = tid * ITEMS;

    const float kval = kern[0];
    const double kd = (double)kval;
    const float* __restrict__ cp = conc + (size_t)b * (LSEQ * NF);
    float* __restrict__ op = out + (size_t)b * (NF * LSEQ);
    const float4* __restrict__ p4 = (const float4*)(cp + (size_t)t0 * NF);

    // ---- phase 1: vectorized load, extract a (col 0) and row sums S ----
    float av[ITEMS], Sv[ITEMS];
    #pragma unroll
    for (int h = 0; h < 2; ++h) {
        float4 q[9];
        #pragma unroll
        for (int m = 0; m < 9; ++m) q[m] = p4[h * 9 + m];
        #pragma unroll
        for (int i = 0; i < 4; ++i) {
            float s = 0.0f;
            #pragma unroll
            for (int c = 0; c < 9; ++c) {
                int idx = 9 * i + c;
                float val = f4c(q[idx >> 2], idx & 3);
                if (c == 0) av[h * 4 + i] = val;
                s += val;
            }
            Sv[h * 4 + i] = s;
        }
    }

    // ---- scan 1: S -> Zp[t] = 1 + inclusive_prefix(S) ----
    double incl[ITEMS];
    double run = 0.0;
    #pragma unroll
    for (int i = 0; i < ITEMS; ++i) { run += (double)Sv[i]; incl[i] = run; }
    double blockTotS;
    double excl = block_scan(run, lane, wid, (double*)PB, &blockTotS);
    #pragma unroll
    for (int i = 0; i < ITEMS; ++i) Zp[t0 + i] = (float)(1.0 + excl + incl[i]);
    __syncthreads();

    // pre-read every Zp value this thread will ever need, then Zp becomes scratch
    float zPf[ITEMS], zQf[ITEMS];
    #pragma unroll
    for (int i = 0; i < ITEMS; ++i) {
        int t = t0 + i;
        zPf[i] = (t >= 14) ? Zp[t - 14] : 1.0f;               // Z(t-14)
        zQf[i] = (t <= LSEQ - 15) ? Zp[t + 13] : 0.0f;        // for W(t+14)
    }
    __syncthreads();

    // ---- scan 2: P_j = a_j * Z(j-14) -> PP in PB ----
    run = 0.0;
    #pragma unroll
    for (int i = 0; i < ITEMS; ++i) { run += (double)av[i] * (double)zPf[i]; incl[i] = run; }
    double dummyTot;
    excl = block_scan(run, lane, wid, (double*)Zp, &dummyTot);
    #pragma unroll
    for (int i = 0; i < ITEMS; ++i) PB[t0 + i] = (float)(excl + incl[i]);
    __syncthreads();

    // c_fwd[t] = k * a_t * (PP[t-16] - PP[t-76])
    float cf[ITEMS];
    #pragma unroll
    for (int i = 0; i < ITEMS; ++i) {
        int t = t0 + i;
        double hi = (t - 16 >= 0) ? (double)PB[t - 16] : 0.0;
        double lo = (t - 76 >= 0) ? (double)PB[t - 76] : 0.0;
        cf[i] = (float)(kd * (double)av[i] * (hi - lo));
    }
    __syncthreads();   // everyone done reading PP

    // ---- scan 3: Q_u = a_u * W(u+14), W(m) = totS + 2 - Zp[m-1] (m<=L-1) else 1 ----
    run = 0.0;
    #pragma unroll
    for (int i = 0; i < ITEMS; ++i) {
        int t = t0 + i;
        double w = (t <= LSEQ - 15) ? (blockTotS + 2.0 - (double)zQf[i]) : 1.0;
        run += (double)av[i] * w;
        incl[i] = run;
    }
    excl = block_scan(run, lane, wid, (double*)Zp, &dummyTot);
    #pragma unroll
    for (int i = 0; i < ITEMS; ++i) PB[t0 + i] = (float)(excl + incl[i]);
    __syncthreads();

    // c_bwd[t] = k * a_t * (prefQ[min(t+75,L-1)] - prefQ[min(t+15,L-1)])
    float cbw[ITEMS];
    #pragma unroll
    for (int i = 0; i < ITEMS; ++i) {
        int t = t0 + i;
        int hiI = t + 75; if (hiI > LSEQ - 1) hiI = LSEQ - 1;
        int loI = t + 15; if (loI > LSEQ - 1) loI = LSEQ - 1;
        double d = (double)PB[hiI] - (double)PB[loI];
        cbw[i] = (float)(kd * (double)av[i] * d);
    }

    // ---- epilogue ----
    const float invZ1 = 1.0f / (float)(1.0 + blockTotS);

    // row 0: (cf*a + a*cbw + a*a) / adj(a) / Z1, clipped
    {
        float fo[ITEMS];
        #pragma unroll
        for (int i = 0; i < ITEMS; ++i) {
            float v = av[i];
            float adjv = (v > 1e-13f) ? v : (v + 1.0f);
            float f = (cf[i] * v + v * cbw[i] + v * v) / adjv * invZ1;
            fo[i] = fminf(fmaxf(f, 0.0f), 0.9999f);
        }
        float4* o0 = (float4*)(op + t0);
        o0[0] = make_float4(fo[0], fo[1], fo[2], fo[3]);
        o0[1] = make_float4(fo[4], fo[5], fo[6], fo[7]);
    }

    // rows 1..8: v*v/adj(v)/Z1 (re-read input; it's L3-resident)
    #pragma unroll
    for (int h = 0; h < 2; ++h) {
        float4 q[9];
        #pragma unroll
        for (int m = 0; m < 9; ++m) q[m] = p4[h * 9 + m];
        #pragma unroll
        for (int r = 1; r < 9; ++r) {
            float4 w;
            #pragma unroll
            for (int i = 0; i < 4; ++i) {
                int idx = 9 * i + r;
                float v = f4c(q[idx >> 2], idx & 3);
                float adjv = (v > 1e-13f) ? v : (v + 1.0f);
                float f = v * v / adjv * invZ1;
                f = fminf(fmaxf(f, 0.0f), 0.9999f);
                if (i == 0) w.x = f;
                else if (i == 1) w.y = f;
                else if (i == 2) w.z = f;
                else w.w = f;
            }
            *(float4*)(op + (size_t)r * LSEQ + t0 + h * 4) = w;
        }
    }
}

extern "C" void kernel_launch(void* const* d_in, const int* in_sizes, int n_in,
                              void* d_out, int out_size, void* d_ws, size_t ws_size,
                              hipStream_t stream) {
    const float* conc = (const float*)d_in[0];
    const float* kern = (const float*)d_in[1];
    float* out = (float*)d_out;
    int B = in_sizes[0] / (LSEQ * NF);
    hipLaunchKernelGGL(kenneth_kernel, dim3(B), dim3(NT), 0, stream, conc, kern, out);
}

// Round 2
// 109.867 us; speedup vs baseline: 1.0821x; 1.0821x over previous
//
#include <hip/hip_runtime.h>

#define LSEQ 8192
#define NF 9
#define CT 4             // tiles per batch
#define TSZ 2048         // tile size
#define NT1 256          // K1 threads
#define NT2 512          // K2 threads
#define IT2 4            // items/thread in K2 (NT2*IT2 == TSZ)
#define NW2 8            // waves per K2 block
#define EOFF 96          // E[i] = prefS(t_start - EOFF + i); main x <-> i = x+96 (16B aligned)
#define EB (TSZ + 184)   // max index used: TSZ+183

__device__ __forceinline__ float f4c(const float4& v, int c) {
    return c == 0 ? v.x : c == 1 ? v.y : c == 2 ? v.z : v.w;
}

template<int NWAVES>
__device__ __forceinline__ double block_scan(double tot, int lane, int wid,
                                             double* swv, double* blockTot) {
    double v = tot;
    #pragma unroll
    for (int off = 1; off < 64; off <<= 1) {
        double n = __shfl_up(v, (unsigned)off, 64);
        if (lane >= off) v += n;
    }
    if (lane == 63) swv[wid] = v;
    __syncthreads();
    double wOff = 0.0, bTot = 0.0;
    #pragma unroll
    for (int w = 0; w < NWAVES; ++w) {
        double t2 = swv[w];
        if (w < wid) wOff += t2;
        bTot += t2;
    }
    __syncthreads();
    *blockTot = bTot;
    return wOff + (v - tot);
}

// ---------------- Kernel 1: per-tile sum of row-sums S ----------------
__global__ __launch_bounds__(NT1) void k1_sums(const float* __restrict__ conc,
                                               double* __restrict__ ws) {
    __shared__ double wsum[NT1 / 64];
    const int bc = blockIdx.x;
    const int b = bc / CT, c = bc % CT;
    const int tid = threadIdx.x, lane = tid & 63, wid = tid >> 6;
    const float* cp = conc + (size_t)b * LSEQ * NF + (size_t)c * TSZ * NF;
    const float4* p4 = (const float4*)(cp + (size_t)tid * 8 * NF);
    double tot = 0.0;
    #pragma unroll
    for (int h = 0; h < 2; ++h) {
        float4 q[9];
        #pragma unroll
        for (int m = 0; m < 9; ++m) q[m] = p4[h * 9 + m];
        float s = 0.f;
        #pragma unroll
        for (int m = 0; m < 9; ++m) s += q[m].x + q[m].y + q[m].z + q[m].w;
        tot += (double)s;
    }
    #pragma unroll
    for (int off = 32; off > 0; off >>= 1) tot += __shfl_down(tot, (unsigned)off, 64);
    if (lane == 0) wsum[wid] = tot;
    __syncthreads();
    if (tid == 0) {
        double s = 0.0;
        #pragma unroll
        for (int w = 0; w < NT1 / 64; ++w) s += wsum[w];
        ws[bc] = s;
    }
}

// ---------------- Kernel 2: per-tile full computation ----------------
__global__ __launch_bounds__(NT2) void k2_main(const float* __restrict__ conc,
                                               const float* __restrict__ kern,
                                               const double* __restrict__ ws,
                                               float* __restrict__ out) {
    __shared__ __align__(16) float E[EB];    // extended prefS
    __shared__ __align__(16) float Am[TSZ];  // a in tile
    __shared__ __align__(16) float PP[TSZ];  // local prefix of P
    __shared__ __align__(16) float PQ[TSZ];  // local prefix of Q
    __shared__ float AH[76];                 // a halo before tile
    __shared__ float AF[75];                 // a halo after tile
    __shared__ float cfB[76];                // boundary fwd window sums (k * sum, no a_t)
    __shared__ float cbB[75];                // boundary bwd window sums
    __shared__ double scr[NW2];

    const int bc = blockIdx.x;
    const int b = bc / CT, c = bc % CT;
    const int t_start = c * TSZ;
    const int tid = threadIdx.x, lane = tid & 63, wid = tid >> 6;
    const int x0 = tid * IT2;

    double offsetS = 0.0, totS = 0.0, sumS_c = 0.0;
    #pragma unroll
    for (int cc = 0; cc < CT; ++cc) {
        double v = ws[b * CT + cc];
        if (cc < c) offsetS += v;
        if (cc == c) sumS_c = v;
        totS += v;
    }

    const double kd = (double)kern[0];
    const float* __restrict__ cp = conc + (size_t)b * LSEQ * NF;
    float* __restrict__ op = out + (size_t)b * NF * LSEQ;

    // ---- main tile load ----
    float av[IT2], Sv[IT2];
    {
        const float4* p4 = (const float4*)(cp + (size_t)(t_start + x0) * NF);
        float4 q[9];
        #pragma unroll
        for (int m = 0; m < 9; ++m) q[m] = p4[m];
        #pragma unroll
        for (int i = 0; i < IT2; ++i) {
            float s = 0.f;
            #pragma unroll
            for (int cc2 = 0; cc2 < 9; ++cc2) {
                int idx = 9 * i + cc2;
                float val = f4c(q[idx >> 2], idx & 3);
                if (cc2 == 0) av[i] = val;
                s += val;
            }
            Sv[i] = s;
            Am[x0 + i] = av[i];
        }
    }

    // ---- halo loads (zero-padded outside [0,LSEQ)) ----
    if (tid < EOFF) {                        // S back-halo -> E[0..96)
        int t = t_start - EOFF + tid;
        float s = 0.f;
        if (t >= 0) {
            const float* r = cp + (size_t)t * NF;
            #pragma unroll
            for (int m = 0; m < 9; ++m) s += r[m];
        }
        E[tid] = s;
    } else if (tid >= 96 && tid < 184) {     // S fwd-halo -> E[96+TSZ .. +88)
        int y = tid - 96;
        int t = t_start + TSZ + y;
        float s = 0.f;
        if (t < LSEQ) {
            const float* r = cp + (size_t)t * NF;
            #pragma unroll
            for (int m = 0; m < 9; ++m) s += r[m];
        }
        E[EOFF + TSZ + y] = s;
    } else if (tid >= 192 && tid < 268) {    // a back-halo
        int i = tid - 192;
        int t = t_start - 76 + i;
        AH[i] = (t >= 0) ? cp[(size_t)t * NF] : 0.f;
    } else if (tid >= 272 && tid < 347) {    // a fwd-halo
        int y = tid - 272;
        int t = t_start + TSZ + y;
        AF[y] = (t < LSEQ) ? cp[(size_t)t * NF] : 0.f;
    }
    __syncthreads();

    // ---- scan 1: S -> E main ----
    double incl[IT2], run = 0.0;
    #pragma unroll
    for (int i = 0; i < IT2; ++i) { run += (double)Sv[i]; incl[i] = run; }
    double bT;
    double excl = block_scan<NW2>(run, lane, wid, scr, &bT);
    #pragma unroll
    for (int i = 0; i < IT2; ++i) E[EOFF + x0 + i] = (float)(offsetS + excl + incl[i]);

    // halo prefS (direct partial sums, staged in registers)
    double hbv = 0.0, hfv = 0.0;
    if (tid < EOFF) {
        double acc = 0.0;
        for (int s2 = tid + 1; s2 < EOFF; ++s2) acc += (double)E[s2];
        hbv = offsetS - acc;
    } else if (tid >= 96 && tid < 184) {
        int y = tid - 96;
        double acc = 0.0;
        for (int s2 = 0; s2 <= y; ++s2) acc += (double)E[EOFF + TSZ + s2];
        hfv = offsetS + sumS_c + acc;
    }
    __syncthreads();
    if (tid < EOFF) E[tid] = (float)hbv;
    else if (tid >= 96 && tid < 184) E[EOFF + TSZ + (tid - 96)] = (float)hfv;
    __syncthreads();

    // ---- scan 2: P_j = a_j * (1 + prefS(j-14)) -> PP ----
    run = 0.0;
    #pragma unroll
    for (int i = 0; i < IT2; ++i) {
        double z = 1.0 + (double)E[x0 + i + (EOFF - 14)];
        run += (double)av[i] * z;
        incl[i] = run;
    }
    double dmy;
    excl = block_scan<NW2>(run, lane, wid, scr, &dmy);
    #pragma unroll
    for (int i = 0; i < IT2; ++i) PP[x0 + i] = (float)(excl + incl[i]);

    // ---- scan 3: Q_u = a_u * (1 + totS - prefS(u+13)) -> PQ ----
    run = 0.0;
    #pragma unroll
    for (int i = 0; i < IT2; ++i) {
        double w = 1.0 + totS - (double)E[x0 + i + (EOFF + 13)];
        run += (double)av[i] * w;
        incl[i] = run;
    }
    excl = block_scan<NW2>(run, lane, wid, scr, &dmy);
    #pragma unroll
    for (int i = 0; i < IT2; ++i) PQ[x0 + i] = (float)(excl + incl[i]);
    __syncthreads();

    // ---- boundary windows: direct 60-term dots (one thread per position) ----
    if (tid < 76) {
        int x = tid;
        double acc = 0.0;
        for (int j = x - 75; j <= x - 16; ++j) {
            float aj = (j >= 0) ? Am[j] : AH[j + 76];
            acc += (double)aj * (1.0 + (double)E[j + (EOFF - 14)]);
        }
        cfB[x] = (float)(kd * acc);
    }
    if (tid >= 256 && tid < 331) {
        int tb = tid - 256;
        int x = TSZ - 75 + tb;
        double acc = 0.0;
        for (int u = x + 16; u <= x + 75; ++u) {
            float au = (u < TSZ) ? Am[u] : AF[u - TSZ];
            acc += (double)au * (1.0 + totS - (double)E[u + (EOFF + 13)]);
        }
        cbB[tb] = (float)(kd * acc);
    }
    __syncthreads();

    // ---- epilogue ----
    const float invZ1 = (float)(1.0 / (1.0 + totS));
    float fo[IT2];
    #pragma unroll
    for (int i = 0; i < IT2; ++i) {
        int x = x0 + i;
        float v = av[i];
        float cf, cb;
        if (x < 76) cf = cfB[x] * v;
        else        cf = (float)(kd * (double)v * ((double)PP[x - 16] - (double)PP[x - 76]));
        if (x >= TSZ - 75) cb = cbB[x - (TSZ - 75)] * v;
        else               cb = (float)(kd * (double)v * ((double)PQ[x + 75] - (double)PQ[x + 15]));
        float adjv = (v > 1e-13f) ? v : (v + 1.0f);
        float f = (cf * v + v * cb + v * v) / adjv * invZ1;
        fo[i] = fminf(fmaxf(f, 0.0f), 0.9999f);
    }
    *(float4*)(op + t_start + x0) = make_float4(fo[0], fo[1], fo[2], fo[3]);

    // rows 1..8: v^2 / adj(v) / Z1 (re-read input; L1/L2-hit)
    {
        const float4* p4 = (const float4*)(cp + (size_t)(t_start + x0) * NF);
        float4 q[9];
        #pragma unroll
        for (int m = 0; m < 9; ++m) q[m] = p4[m];
        #pragma unroll
        for (int r = 1; r < 9; ++r) {
            float4 w;
            float* wp = (float*)&w;
            #pragma unroll
            for (int i = 0; i < IT2; ++i) {
                int idx = 9 * i + r;
                float v = f4c(q[idx >> 2], idx & 3);
                float adjv = (v > 1e-13f) ? v : (v + 1.0f);
                float f = v * v / adjv * invZ1;
                wp[i] = fminf(fmaxf(f, 0.0f), 0.9999f);
            }
            *(float4*)(op + (size_t)r * LSEQ + t_start + x0) = w;
        }
    }
}

extern "C" void kernel_launch(void* const* d_in, const int* in_sizes, int n_in,
                              void* d_out, int out_size, void* d_ws, size_t ws_size,
                              hipStream_t stream) {
    const float* conc = (const float*)d_in[0];
    const float* kern = (const float*)d_in[1];
    float* out = (float*)d_out;
    double* wsd = (double*)d_ws;
    int B = in_sizes[0] / (LSEQ * NF);
    hipLaunchKernelGGL(k1_sums, dim3(B * CT), dim3(NT1), 0, stream, conc, wsd);
    hipLaunchKernelGGL(k2_main, dim3(B * CT), dim3(NT2), 0, stream, conc, kern, wsd, out);
}